// Round 1
// baseline (1401.903 us; speedup 1.0000x reference)
//
#include <hip/hip_runtime.h>
#include <math.h>

#define NH 4
#define DIM 512
#define VDIM 512
#define QDIM 1024
#define KS 100
#define KN 100
#define TEMPERATURE 0.5f
#define BS 8
#define TS 2048
#define NHD (NH * DIM)          // 2048

// workspace layout (in floats)
#define WS_QUERY  0                       // 8*2048            = 16384
#define WS_QTAB   16384                   // 202*512           = 103424
#define WS_ENERGY (16384 + 103424)        // 8*4*2048          = 65536
#define WS_CTX    (WS_ENERGY + 65536)     // 8*2048            = 16384
#define WS_TOTAL  (WS_CTX + 16384)

// ---------------------------------------------------------------------------
// query[b, o] = tanh(dec_state[b,:] . Wq[o,:] + bq[o]);  one wave per output
// ---------------------------------------------------------------------------
__global__ void k_query(const float* __restrict__ dec, const float* __restrict__ Wq,
                        const float* __restrict__ bq, float* __restrict__ query) {
    int w = (blockIdx.x * blockDim.x + threadIdx.x) >> 6;
    int lane = threadIdx.x & 63;
    int b = w >> 11;           // 2048 outputs per batch
    int o = w & 2047;
    const float* dr = dec + b * QDIM;
    const float* wr = Wq + o * QDIM;
    float s = 0.f;
    #pragma unroll
    for (int i = 0; i < QDIM / 64; ++i) s = fmaf(dr[lane + 64 * i], wr[lane + 64 * i], s);
    #pragma unroll
    for (int off = 32; off > 0; off >>= 1) s += __shfl_down(s, off);
    if (lane == 0) query[b * NHD + o] = tanhf(s + bq[o]);
}

// ---------------------------------------------------------------------------
// Qtab[j, d] = sum_k proj[d,k] * P[k,j],  P[k,j] = sum_{dt<j} sum_h convw[k,h,dt]
// conv[b,k,t] = (P[k,hi+1]-P[k,lo]) / len_b  with lo=max(0,KS-t),
// hi=min(2KS, KS-t+len-1)  -> loc[b,t,d] = tanh((Qtab[hi+1,d]-Qtab[lo,d])/len)
// ---------------------------------------------------------------------------
__global__ void k_qtab(const float* __restrict__ convw, const float* __restrict__ projw,
                       float* __restrict__ Qtab) {
    int j = blockIdx.x;       // 0..201
    __shared__ float P[KN];
    int tid = threadIdx.x;    // 512 threads
    if (tid < KN) {
        const float* wr = convw + tid * (NH * (2 * KS + 1));
        float s = 0.f;
        for (int dt = 0; dt < j; ++dt)
            s += wr[dt] + wr[201 + dt] + wr[402 + dt] + wr[603 + dt];
        P[tid] = s;
    }
    __syncthreads();
    const float* pr = projw + tid * KN;
    float s = 0.f;
    #pragma unroll 4
    for (int k = 0; k < KN; ++k) s = fmaf(pr[k], P[k], s);
    Qtab[j * DIM + tid] = s;
}

// ---------------------------------------------------------------------------
// Energy pass: C = enc_feat[b] @ Wk^T (128x128 tile), fused epilogue:
//   e_part[b,h,t] += sum_n tanh(tanh(C+bk) + query + loc) * gen_w
// ---------------------------------------------------------------------------
__global__ __launch_bounds__(256) void k_energy(
    const float* __restrict__ enc, const float* __restrict__ Wk,
    const float* __restrict__ bk, const float* __restrict__ gen_w,
    const int* __restrict__ enc_len, const float* __restrict__ query,
    const float* __restrict__ Qtab, float* __restrict__ energy) {
    const int t0 = blockIdx.x * 128;
    const int n0 = blockIdx.y * 128;
    const int b  = blockIdx.z;
    const int tid = threadIdx.x;
    const int ty = tid >> 4, tx = tid & 15;

    __shared__ float smem[4096];
    float* As = smem;          // [16][128] transposed: As[kk][m]
    float* Bs = smem + 2048;   // [16][128]

    float acc[8][8];
    #pragma unroll
    for (int i = 0; i < 8; ++i)
        #pragma unroll
        for (int j = 0; j < 8; ++j) acc[i][j] = 0.f;

    const float* Abase = enc + (size_t)(b * TS + t0) * VDIM;
    const float* Bbase = Wk + (size_t)n0 * VDIM;

    for (int k0 = 0; k0 < VDIM; k0 += 16) {
        #pragma unroll
        for (int i = 0; i < 2; ++i) {
            int f4 = tid + i * 256;           // 512 float4 slots: row = f4>>2, c4 = f4&3
            int row = f4 >> 2, c4 = f4 & 3;
            float4 va = *(const float4*)(Abase + (size_t)row * VDIM + k0 + c4 * 4);
            As[(c4 * 4 + 0) * 128 + row] = va.x;
            As[(c4 * 4 + 1) * 128 + row] = va.y;
            As[(c4 * 4 + 2) * 128 + row] = va.z;
            As[(c4 * 4 + 3) * 128 + row] = va.w;
            float4 vb = *(const float4*)(Bbase + (size_t)row * VDIM + k0 + c4 * 4);
            Bs[(c4 * 4 + 0) * 128 + row] = vb.x;
            Bs[(c4 * 4 + 1) * 128 + row] = vb.y;
            Bs[(c4 * 4 + 2) * 128 + row] = vb.z;
            Bs[(c4 * 4 + 3) * 128 + row] = vb.w;
        }
        __syncthreads();
        #pragma unroll
        for (int kk = 0; kk < 16; ++kk) {
            float a[8], bb[8];
            *(float4*)&a[0]  = *(const float4*)&As[kk * 128 + ty * 8];
            *(float4*)&a[4]  = *(const float4*)&As[kk * 128 + ty * 8 + 4];
            *(float4*)&bb[0] = *(const float4*)&Bs[kk * 128 + tx * 8];
            *(float4*)&bb[4] = *(const float4*)&Bs[kk * 128 + tx * 8 + 4];
            #pragma unroll
            for (int i = 0; i < 8; ++i)
                #pragma unroll
                for (int j = 0; j < 8; ++j) acc[i][j] = fmaf(a[i], bb[j], acc[i][j]);
        }
        __syncthreads();
    }

    // epilogue: reduce over the 128 n-columns (all within one head: 512%128==0)
    const int h = n0 >> 9;
    const int len = enc_len[b];
    const float inv_len = 1.0f / (float)len;
    float msum[8];
    #pragma unroll
    for (int i = 0; i < 8; ++i) {
        int t = t0 + ty * 8 + i;
        int lo = KS - t; if (lo < 0) lo = 0;
        int hi = KS - t + len - 1; if (hi > 2 * KS) hi = 2 * KS;
        bool has = (hi >= lo);
        float s = 0.f;
        #pragma unroll
        for (int j = 0; j < 8; ++j) {
            int n = n0 + tx * 8 + j;
            int d = n & (DIM - 1);
            float key = tanhf(acc[i][j] + bk[n]);
            float conv = has ? (Qtab[(hi + 1) * DIM + d] - Qtab[lo * DIM + d]) * inv_len : 0.f;
            float loc = tanhf(conv);
            float e = tanhf(key + query[b * NHD + n] + loc);
            s = fmaf(e, gen_w[d], s);
        }
        msum[i] = s;
    }
    float* red = smem;   // [128][16]
    #pragma unroll
    for (int i = 0; i < 8; ++i) red[(ty * 8 + i) * 16 + tx] = msum[i];
    __syncthreads();
    if (tid < 128) {
        float s = 0.f;
        #pragma unroll
        for (int x = 0; x < 16; ++x) s += red[tid * 16 + x];
        atomicAdd(&energy[(size_t)(b * NH + h) * TS + t0 + tid], s);
    }
}

// ---------------------------------------------------------------------------
// softmax over t (masked), writes attn to d_out[0 : 8*4*2048]
// ---------------------------------------------------------------------------
__global__ void k_softmax(const float* __restrict__ energy, const int* __restrict__ enc_len,
                          const float* __restrict__ gen_b, float* __restrict__ attn) {
    int bh = blockIdx.x;          // 0..31
    int b = bh >> 2;
    int len = enc_len[b];
    int tid = threadIdx.x;        // 256
    const float gb = gen_b[0];
    float ev[8];
    float mx = -INFINITY;
    #pragma unroll
    for (int i = 0; i < 8; ++i) {
        int t = i * 256 + tid;
        float e = (t < len) ? (energy[(size_t)bh * TS + t] + gb) * (1.0f / TEMPERATURE)
                            : -INFINITY;
        ev[i] = e;
        mx = fmaxf(mx, e);
    }
    __shared__ float sred[256];
    sred[tid] = mx; __syncthreads();
    for (int off = 128; off > 0; off >>= 1) {
        if (tid < off) sred[tid] = fmaxf(sred[tid], sred[tid + off]);
        __syncthreads();
    }
    mx = sred[0]; __syncthreads();
    float ls = 0.f;
    #pragma unroll
    for (int i = 0; i < 8; ++i) {
        float ex = expf(ev[i] - mx);    // -inf -> 0
        ev[i] = ex;
        ls += ex;
    }
    sred[tid] = ls; __syncthreads();
    for (int off = 128; off > 0; off >>= 1) {
        if (tid < off) sred[tid] += sred[tid + off];
        __syncthreads();
    }
    float inv = 1.0f / sred[0];
    #pragma unroll
    for (int i = 0; i < 8; ++i)
        attn[(size_t)bh * TS + i * 256 + tid] = ev[i] * inv;
}

// ---------------------------------------------------------------------------
// ctx pass: C = enc_feat[b] @ Wv^T, fused: ctx[b,n] += sum_t attn * tanh(C+bv)
// ---------------------------------------------------------------------------
__global__ __launch_bounds__(256) void k_ctx(
    const float* __restrict__ enc, const float* __restrict__ Wv,
    const float* __restrict__ bv, const float* __restrict__ attn,
    float* __restrict__ ctx) {
    const int t0 = blockIdx.x * 128;
    const int n0 = blockIdx.y * 128;
    const int b  = blockIdx.z;
    const int tid = threadIdx.x;
    const int ty = tid >> 4, tx = tid & 15;

    __shared__ float smem[4096];
    float* As = smem;
    float* Bs = smem + 2048;

    float acc[8][8];
    #pragma unroll
    for (int i = 0; i < 8; ++i)
        #pragma unroll
        for (int j = 0; j < 8; ++j) acc[i][j] = 0.f;

    const float* Abase = enc + (size_t)(b * TS + t0) * VDIM;
    const float* Bbase = Wv + (size_t)n0 * VDIM;

    for (int k0 = 0; k0 < VDIM; k0 += 16) {
        #pragma unroll
        for (int i = 0; i < 2; ++i) {
            int f4 = tid + i * 256;
            int row = f4 >> 2, c4 = f4 & 3;
            float4 va = *(const float4*)(Abase + (size_t)row * VDIM + k0 + c4 * 4);
            As[(c4 * 4 + 0) * 128 + row] = va.x;
            As[(c4 * 4 + 1) * 128 + row] = va.y;
            As[(c4 * 4 + 2) * 128 + row] = va.z;
            As[(c4 * 4 + 3) * 128 + row] = va.w;
            float4 vb = *(const float4*)(Bbase + (size_t)row * VDIM + k0 + c4 * 4);
            Bs[(c4 * 4 + 0) * 128 + row] = vb.x;
            Bs[(c4 * 4 + 1) * 128 + row] = vb.y;
            Bs[(c4 * 4 + 2) * 128 + row] = vb.z;
            Bs[(c4 * 4 + 3) * 128 + row] = vb.w;
        }
        __syncthreads();
        #pragma unroll
        for (int kk = 0; kk < 16; ++kk) {
            float a[8], bb[8];
            *(float4*)&a[0]  = *(const float4*)&As[kk * 128 + ty * 8];
            *(float4*)&a[4]  = *(const float4*)&As[kk * 128 + ty * 8 + 4];
            *(float4*)&bb[0] = *(const float4*)&Bs[kk * 128 + tx * 8];
            *(float4*)&bb[4] = *(const float4*)&Bs[kk * 128 + tx * 8 + 4];
            #pragma unroll
            for (int i = 0; i < 8; ++i)
                #pragma unroll
                for (int j = 0; j < 8; ++j) acc[i][j] = fmaf(a[i], bb[j], acc[i][j]);
        }
        __syncthreads();
    }

    // epilogue: attn-weighted reduce over the 128 t-rows
    const int h = n0 >> 9;
    float att[8];
    #pragma unroll
    for (int i = 0; i < 8; ++i)
        att[i] = attn[(size_t)(b * NH + h) * TS + t0 + ty * 8 + i];
    float nsum[8];
    #pragma unroll
    for (int j = 0; j < 8; ++j) {
        int n = n0 + tx * 8 + j;
        float bvn = bv[n];
        float s = 0.f;
        #pragma unroll
        for (int i = 0; i < 8; ++i)
            s = fmaf(att[i], tanhf(acc[i][j] + bvn), s);
        nsum[j] = s;
    }
    float* red = smem;   // [128][16]
    #pragma unroll
    for (int j = 0; j < 8; ++j) red[(tx * 8 + j) * 16 + ty] = nsum[j];
    __syncthreads();
    if (tid < 128) {
        float s = 0.f;
        #pragma unroll
        for (int x = 0; x < 16; ++x) s += red[tid * 16 + x];
        atomicAdd(&ctx[(size_t)b * NHD + n0 + tid], s);
    }
}

// ---------------------------------------------------------------------------
// context[b,o] = ctx[b,:] . merge_w[o,:] + merge_b[o];  one wave per output
// ---------------------------------------------------------------------------
__global__ void k_merge(const float* __restrict__ ctx, const float* __restrict__ mw,
                        const float* __restrict__ mb, float* __restrict__ out) {
    int w = (blockIdx.x * blockDim.x + threadIdx.x) >> 6;
    int lane = threadIdx.x & 63;
    int b = w >> 9;            // 512 outputs per batch
    int o = w & 511;
    const float* c = ctx + (size_t)b * NHD;
    const float* wr = mw + (size_t)o * NHD;
    float s = 0.f;
    #pragma unroll
    for (int i = 0; i < NHD / 64; ++i) s = fmaf(c[lane + 64 * i], wr[lane + 64 * i], s);
    #pragma unroll
    for (int off = 32; off > 0; off >>= 1) s += __shfl_down(s, off);
    if (lane == 0) out[b * VDIM + o] = s + mb[o];
}

extern "C" void kernel_launch(void* const* d_in, const int* in_sizes, int n_in,
                              void* d_out, int out_size, void* d_ws, size_t ws_size,
                              hipStream_t stream) {
    const float* dec     = (const float*)d_in[0];
    const float* enc     = (const float*)d_in[1];
    const int*   enc_len = (const int*)d_in[2];
    const float* Wq      = (const float*)d_in[3];
    const float* bq      = (const float*)d_in[4];
    const float* Wk      = (const float*)d_in[5];
    const float* bk      = (const float*)d_in[6];
    const float* Wv      = (const float*)d_in[7];
    const float* bv      = (const float*)d_in[8];
    const float* convw   = (const float*)d_in[9];
    const float* projw   = (const float*)d_in[10];
    const float* gen_w   = (const float*)d_in[11];
    const float* gen_b   = (const float*)d_in[12];
    const float* merge_w = (const float*)d_in[13];
    const float* merge_b = (const float*)d_in[14];

    float* out   = (float*)d_out;               // attn [65536] ++ context [4096]
    float* ws    = (float*)d_ws;
    float* query = ws + WS_QUERY;
    float* Qtab  = ws + WS_QTAB;
    float* energy= ws + WS_ENERGY;
    float* ctx   = ws + WS_CTX;

    // zero the atomic accumulators (energy + ctx are contiguous)
    hipMemsetAsync(energy, 0, (65536 + 16384) * sizeof(float), stream);

    k_query<<<dim3(BS * NHD / 4), dim3(256), 0, stream>>>(dec, Wq, bq, query);
    k_qtab<<<dim3(2 * KS + 2), dim3(512), 0, stream>>>(convw, projw, Qtab);
    k_energy<<<dim3(TS / 128, NHD / 128, BS), dim3(256), 0, stream>>>(
        enc, Wk, bk, gen_w, enc_len, query, Qtab, energy);
    k_softmax<<<dim3(BS * NH), dim3(256), 0, stream>>>(energy, enc_len, gen_b, out);
    k_ctx<<<dim3(TS / 128, NHD / 128, BS), dim3(256), 0, stream>>>(
        enc, Wv, bv, out, ctx);
    k_merge<<<dim3(BS * VDIM / 4), dim3(256), 0, stream>>>(ctx, merge_w, merge_b, out + 65536);
}

// Round 2
// 459.357 us; speedup vs baseline: 3.0519x; 3.0519x over previous
//
#include <hip/hip_runtime.h>
#include <math.h>

#define NH 4
#define DIM 512
#define VDIM 512
#define QDIM 1024
#define KS 100
#define KN 100
#define TEMPERATURE 0.5f
#define BS 8
#define TS 2048
#define NHD (NH * DIM)          // 2048

// workspace layout
#define WS_QUERY  0                       // 16384 floats
#define WS_QTAB   16384                   // 202*512 = 103424
#define WS_ENERGY 119808                  // 65536
#define WS_CTX    185344                  // 16384
#define WS_F32_END 201728                 // floats -> 806912 bytes (16B aligned)
// bf16 region at byte 806912: enc_bf [8388608], wk_bf [1048576], wv_bf [1048576]

typedef __bf16 bf16x8 __attribute__((ext_vector_type(8)));
typedef __bf16 bf16x4 __attribute__((ext_vector_type(4)));
typedef float  f32x4  __attribute__((ext_vector_type(4)));

#define AS1(p) ((const __attribute__((address_space(1))) void*)(p))
#define AS3(p) ((__attribute__((address_space(3))) void*)(p))

// ---------------------------------------------------------------------------
// fp32 -> bf16 conversion (vectorized, grid-stride free: exact grid)
// ---------------------------------------------------------------------------
__global__ void k_cvt(const float* __restrict__ in, __bf16* __restrict__ out, int n4) {
    int i = blockIdx.x * blockDim.x + threadIdx.x;
    if (i < n4) {
        float4 v = ((const float4*)in)[i];
        bf16x4 o;
        o[0] = (__bf16)v.x; o[1] = (__bf16)v.y; o[2] = (__bf16)v.z; o[3] = (__bf16)v.w;
        ((bf16x4*)out)[i] = o;
    }
}

// ---------------------------------------------------------------------------
// query[b, o] = tanh(dec_state[b,:] . Wq[o,:] + bq[o]);  one wave per output
// ---------------------------------------------------------------------------
__global__ void k_query(const float* __restrict__ dec, const float* __restrict__ Wq,
                        const float* __restrict__ bq, float* __restrict__ query) {
    int w = (blockIdx.x * blockDim.x + threadIdx.x) >> 6;
    int lane = threadIdx.x & 63;
    int b = w >> 11;
    int o = w & 2047;
    const float* dr = dec + b * QDIM;
    const float* wr = Wq + o * QDIM;
    float s = 0.f;
    #pragma unroll
    for (int i = 0; i < QDIM / 64; ++i) s = fmaf(dr[lane + 64 * i], wr[lane + 64 * i], s);
    #pragma unroll
    for (int off = 32; off > 0; off >>= 1) s += __shfl_down(s, off);
    if (lane == 0) query[b * NHD + o] = tanhf(s + bq[o]);
}

// ---------------------------------------------------------------------------
// Qtab[j,d] = sum_k proj[d,k] * P[k,j], P[k,j] = sum_{dt<j} sum_h convw[k,h,dt]
// ---------------------------------------------------------------------------
__global__ void k_qtab(const float* __restrict__ convw, const float* __restrict__ projw,
                       float* __restrict__ Qtab) {
    int j = blockIdx.x;       // 0..201
    __shared__ float P[KN];
    int tid = threadIdx.x;    // 512
    if (tid < KN) {
        const float* wr = convw + tid * (NH * (2 * KS + 1));
        float s = 0.f;
        for (int dt = 0; dt < j; ++dt)
            s += wr[dt] + wr[201 + dt] + wr[402 + dt] + wr[603 + dt];
        P[tid] = s;
    }
    __syncthreads();
    const float* pr = projw + tid * KN;
    float s = 0.f;
    #pragma unroll 4
    for (int k = 0; k < KN; ++k) s = fmaf(pr[k], P[k], s);
    Qtab[j * DIM + tid] = s;
}

// ===========================================================================
// MFMA GEMM core (shared by both passes):
//  - 128x128 block tile, BK=64, 256 threads = 4 waves in 2x2 wave grid
//  - A = enc_bf[b] rows t0..t0+127 (row-major K=512)
//  - B = W rows n0..n0+127 (row-major K=512, i.e. B^T layout)
//  - LDS slots of 8 bf16 (16B): slot(m, j) holds global chunk c = j ^ (m&7)
//    -> global_load_lds lanes 0..7 cover one 128B row segment (coalesced)
//    -> ds_read_b128 fragment reads are 2-way-conflict-free
// ===========================================================================
#define STAGE_TILE(dst, base)                                                     \
    {                                                                             \
        _Pragma("unroll")                                                         \
        for (int q = 0; q < 4; ++q) {                                             \
            int slotbase = (w * 4 + q) * 64;                                      \
            int m = (slotbase + lane) >> 3;                                       \
            int c = (lane & 7) ^ (lane >> 3);                                     \
            const __bf16* gp = (base) + (size_t)m * VDIM + k0 + c * 8;            \
            __builtin_amdgcn_global_load_lds(AS1(gp), AS3(dst + slotbase * 8),    \
                                             16, 0, 0);                           \
        }                                                                         \
    }

#define GEMM_MAIN(Bglobal)                                                        \
    const int t0 = blockIdx.x * 128;                                              \
    const int n0 = blockIdx.y * 128;                                              \
    const int b  = blockIdx.z;                                                    \
    const int tid = threadIdx.x;                                                  \
    const int w = tid >> 6, lane = tid & 63;                                      \
    const int wy = w >> 1, wx = w & 1;                                            \
    const int col = lane & 15, quad = lane >> 4;                                  \
    __shared__ __bf16 Ash[128 * 64];                                              \
    __shared__ __bf16 Bsh[128 * 64];                                              \
    f32x4 acc[4][4];                                                              \
    _Pragma("unroll")                                                             \
    for (int i = 0; i < 4; ++i)                                                   \
        _Pragma("unroll")                                                         \
        for (int j = 0; j < 4; ++j) acc[i][j] = (f32x4)0.f;                       \
    const __bf16* Abase = enc_bf + ((size_t)b * TS + t0) * VDIM;                  \
    const __bf16* Bbase = (Bglobal) + (size_t)n0 * VDIM;                          \
    for (int k0 = 0; k0 < VDIM; k0 += 64) {                                       \
        STAGE_TILE(Ash, Abase)                                                    \
        STAGE_TILE(Bsh, Bbase)                                                    \
        __syncthreads();                                                          \
        _Pragma("unroll")                                                         \
        for (int ks = 0; ks < 2; ++ks) {                                          \
            bf16x8 af[4], bf[4];                                                  \
            int jslot = ((ks * 4 + quad) ^ (col & 7));                            \
            _Pragma("unroll")                                                     \
            for (int i = 0; i < 4; ++i) {                                         \
                int m = wy * 64 + i * 16 + col;                                   \
                af[i] = *(const bf16x8*)(Ash + (m * 8 + jslot) * 8);              \
            }                                                                     \
            _Pragma("unroll")                                                     \
            for (int j = 0; j < 4; ++j) {                                         \
                int n = wx * 64 + j * 16 + col;                                   \
                bf[j] = *(const bf16x8*)(Bsh + (n * 8 + jslot) * 8);              \
            }                                                                     \
            _Pragma("unroll")                                                     \
            for (int i = 0; i < 4; ++i)                                           \
                _Pragma("unroll")                                                 \
                for (int j = 0; j < 4; ++j)                                       \
                    acc[i][j] = __builtin_amdgcn_mfma_f32_16x16x32_bf16(          \
                        af[i], bf[j], acc[i][j], 0, 0, 0);                        \
        }                                                                         \
        __syncthreads();                                                          \
    }
// C/D layout: acc[i][j][r] = C[t0+wy*64+i*16+quad*4+r][n0+wx*64+j*16+col]

// ---------------------------------------------------------------------------
// Energy pass: C = enc @ Wk^T, epilogue:
//   energy[b,h,t] += sum_n tanh(tanh(C)+query+tanh(conv)) * gen_w[d]
// ---------------------------------------------------------------------------
__global__ __launch_bounds__(256) void k_energy(
    const __bf16* __restrict__ enc_bf, const __bf16* __restrict__ wk_bf,
    const float* __restrict__ bk, const float* __restrict__ gen_w,
    const int* __restrict__ enc_len, const float* __restrict__ query,
    const float* __restrict__ Qtab, float* __restrict__ energy) {
    GEMM_MAIN(wk_bf)

    const int h = n0 >> 9;
    const int len = enc_len[b];
    const float inv_len = 1.0f / (float)len;
    float qv[4], gw[4], bkv[4];
    int dj[4];
    #pragma unroll
    for (int j = 0; j < 4; ++j) {
        int n = n0 + wx * 64 + j * 16 + col;
        dj[j] = n & (DIM - 1);
        qv[j] = query[b * NHD + n];
        gw[j] = gen_w[dj[j]];
        bkv[j] = bk[n];
    }
    #pragma unroll
    for (int i = 0; i < 4; ++i) {
        #pragma unroll
        for (int r = 0; r < 4; ++r) {
            int t = t0 + wy * 64 + i * 16 + quad * 4 + r;
            int lo = KS - t; if (lo < 0) lo = 0;
            int hi = KS - t + len - 1; if (hi > 2 * KS) hi = 2 * KS;
            bool has = (hi >= lo);
            float s = 0.f;
            #pragma unroll
            for (int j = 0; j < 4; ++j) {
                float conv = has
                    ? (Qtab[(hi + 1) * DIM + dj[j]] - Qtab[lo * DIM + dj[j]]) * inv_len
                    : 0.f;
                float key = tanhf(acc[i][j][r] + bkv[j]);
                float e = tanhf(key + qv[j] + tanhf(conv));
                s = fmaf(e, gw[j], s);
            }
            s += __shfl_xor(s, 1); s += __shfl_xor(s, 2);
            s += __shfl_xor(s, 4); s += __shfl_xor(s, 8);
            if (col == 0) atomicAdd(&energy[(size_t)(b * NH + h) * TS + t], s);
        }
    }
}

// ---------------------------------------------------------------------------
// softmax over t (masked), writes attn to d_out[0 : 8*4*2048]
// ---------------------------------------------------------------------------
__global__ void k_softmax(const float* __restrict__ energy, const int* __restrict__ enc_len,
                          const float* __restrict__ gen_b, float* __restrict__ attn) {
    int bh = blockIdx.x;
    int b = bh >> 2;
    int len = enc_len[b];
    int tid = threadIdx.x;        // 256
    const float gb = gen_b[0];
    float ev[8];
    float mx = -INFINITY;
    #pragma unroll
    for (int i = 0; i < 8; ++i) {
        int t = i * 256 + tid;
        float e = (t < len) ? (energy[(size_t)bh * TS + t] + gb) * (1.0f / TEMPERATURE)
                            : -INFINITY;
        ev[i] = e;
        mx = fmaxf(mx, e);
    }
    __shared__ float sred[256];
    sred[tid] = mx; __syncthreads();
    for (int off = 128; off > 0; off >>= 1) {
        if (tid < off) sred[tid] = fmaxf(sred[tid], sred[tid + off]);
        __syncthreads();
    }
    mx = sred[0]; __syncthreads();
    float ls = 0.f;
    #pragma unroll
    for (int i = 0; i < 8; ++i) {
        float ex = expf(ev[i] - mx);
        ev[i] = ex;
        ls += ex;
    }
    sred[tid] = ls; __syncthreads();
    for (int off = 128; off > 0; off >>= 1) {
        if (tid < off) sred[tid] += sred[tid + off];
        __syncthreads();
    }
    float inv = 1.0f / sred[0];
    #pragma unroll
    for (int i = 0; i < 8; ++i)
        attn[(size_t)bh * TS + i * 256 + tid] = ev[i] * inv;
}

// ---------------------------------------------------------------------------
// ctx pass: C = enc @ Wv^T, epilogue: ctx[b,n] += sum_t attn * tanh(C + bv)
// ---------------------------------------------------------------------------
__global__ __launch_bounds__(256) void k_ctx(
    const __bf16* __restrict__ enc_bf, const __bf16* __restrict__ wv_bf,
    const float* __restrict__ bv, const float* __restrict__ attn,
    float* __restrict__ ctx) {
    GEMM_MAIN(wv_bf)

    const int h = n0 >> 9;
    float att[4][4];
    #pragma unroll
    for (int i = 0; i < 4; ++i)
        #pragma unroll
        for (int r = 0; r < 4; ++r)
            att[i][r] = attn[(size_t)(b * NH + h) * TS + t0 + wy * 64 + i * 16 + quad * 4 + r];
    #pragma unroll
    for (int j = 0; j < 4; ++j) {
        int n = n0 + wx * 64 + j * 16 + col;
        float bvn = bv[n];
        float s = 0.f;
        #pragma unroll
        for (int i = 0; i < 4; ++i)
            #pragma unroll
            for (int r = 0; r < 4; ++r)
                s = fmaf(att[i][r], tanhf(acc[i][j][r] + bvn), s);
        s += __shfl_xor(s, 16); s += __shfl_xor(s, 32);
        if (quad == 0) atomicAdd(&ctx[(size_t)b * NHD + n], s);
    }
}

// ---------------------------------------------------------------------------
// context[b,o] = ctx[b,:] . merge_w[o,:] + merge_b[o];  one wave per output
// ---------------------------------------------------------------------------
__global__ void k_merge(const float* __restrict__ ctx, const float* __restrict__ mw,
                        const float* __restrict__ mb, float* __restrict__ out) {
    int w = (blockIdx.x * blockDim.x + threadIdx.x) >> 6;
    int lane = threadIdx.x & 63;
    int b = w >> 9;
    int o = w & 511;
    const float* c = ctx + (size_t)b * NHD;
    const float* wr = mw + (size_t)o * NHD;
    float s = 0.f;
    #pragma unroll
    for (int i = 0; i < NHD / 64; ++i) s = fmaf(c[lane + 64 * i], wr[lane + 64 * i], s);
    #pragma unroll
    for (int off = 32; off > 0; off >>= 1) s += __shfl_down(s, off);
    if (lane == 0) out[b * VDIM + o] = s + mb[o];
}

extern "C" void kernel_launch(void* const* d_in, const int* in_sizes, int n_in,
                              void* d_out, int out_size, void* d_ws, size_t ws_size,
                              hipStream_t stream) {
    const float* dec     = (const float*)d_in[0];
    const float* enc     = (const float*)d_in[1];
    const int*   enc_len = (const int*)d_in[2];
    const float* Wq      = (const float*)d_in[3];
    const float* bq      = (const float*)d_in[4];
    const float* Wk      = (const float*)d_in[5];
    const float* bk      = (const float*)d_in[6];
    const float* Wv      = (const float*)d_in[7];
    const float* bv      = (const float*)d_in[8];
    const float* convw   = (const float*)d_in[9];
    const float* projw   = (const float*)d_in[10];
    const float* gen_w   = (const float*)d_in[11];
    const float* gen_b   = (const float*)d_in[12];
    const float* merge_w = (const float*)d_in[13];
    const float* merge_b = (const float*)d_in[14];

    float* out   = (float*)d_out;               // attn [65536] ++ context [4096]
    float* ws    = (float*)d_ws;
    float* query = ws + WS_QUERY;
    float* Qtab  = ws + WS_QTAB;
    float* energy= ws + WS_ENERGY;
    float* ctx   = ws + WS_CTX;
    __bf16* enc_bf = (__bf16*)((char*)d_ws + (size_t)WS_F32_END * 4);
    __bf16* wk_bf  = enc_bf + (size_t)BS * TS * VDIM;      // 8388608
    __bf16* wv_bf  = wk_bf + (size_t)NHD * VDIM;           // +1048576

    // zero atomic accumulators (energy + ctx contiguous)
    hipMemsetAsync(energy, 0, (65536 + 16384) * sizeof(float), stream);

    k_cvt<<<dim3((BS * TS * VDIM / 4 + 255) / 256), dim3(256), 0, stream>>>(
        enc, enc_bf, BS * TS * VDIM / 4);
    k_cvt<<<dim3((NHD * VDIM / 4 + 255) / 256), dim3(256), 0, stream>>>(
        Wk, wk_bf, NHD * VDIM / 4);
    k_cvt<<<dim3((NHD * VDIM / 4 + 255) / 256), dim3(256), 0, stream>>>(
        Wv, wv_bf, NHD * VDIM / 4);
    k_query<<<dim3(BS * NHD / 4), dim3(256), 0, stream>>>(dec, Wq, bq, query);
    k_qtab<<<dim3(2 * KS + 2), dim3(512), 0, stream>>>(convw, projw, Qtab);
    k_energy<<<dim3(TS / 128, NHD / 128, BS), dim3(256), 0, stream>>>(
        enc_bf, wk_bf, bk, gen_w, enc_len, query, Qtab, energy);
    k_softmax<<<dim3(BS * NH), dim3(256), 0, stream>>>(energy, enc_len, gen_b, out);
    k_ctx<<<dim3(TS / 128, NHD / 128, BS), dim3(256), 0, stream>>>(
        enc_bf, wv_bf, bv, out, ctx);
    k_merge<<<dim3(BS * VDIM / 4), dim3(256), 0, stream>>>(ctx, merge_w, merge_b, out + 65536);
}

// Round 3
// 427.276 us; speedup vs baseline: 3.2810x; 1.0751x over previous
//
#include <hip/hip_runtime.h>
#include <math.h>

#define NH 4
#define DIM 512
#define VDIM 512
#define QDIM 1024
#define KS 100
#define KN 100
#define TEMPERATURE 0.5f
#define BS 8
#define TS 2048
#define NHD (NH * DIM)          // 2048

// workspace layout (floats)
#define WS_QUERY  0                       // 16384
#define WS_QTAB   16384                   // 202*512 = 103424
#define WS_ENERGY 119808                  // 65536
#define WS_CTX    185344                  // 16384
#define WS_LOCI   201728                  // 8*512 = 4096
#define WS_F32_END 205824                 // -> 823296 bytes (16B aligned)
// bf16 region: enc_bf [8388608], wk_bf [1048576], wv_bf [1048576]

typedef __bf16 bf16x8 __attribute__((ext_vector_type(8)));
typedef __bf16 bf16x4 __attribute__((ext_vector_type(4)));
typedef float  f32x4  __attribute__((ext_vector_type(4)));

#define AS1(p) ((const __attribute__((address_space(1))) void*)(p))
#define AS3(p) ((__attribute__((address_space(3))) void*)(p))

// tanh(x) = (e-1)/(e+1), e = exp(2x); clamp to +-9 so e never overflows.
// ~8 VALU ops (v_exp_f32 + v_rcp_f32) vs ~25+ for libm tanhf. abs err ~1e-6.
__device__ __forceinline__ float fast_tanh(float x) {
    float xc = fminf(fmaxf(x, -9.0f), 9.0f);
    float e = __expf(2.0f * xc);
    return __fdividef(e - 1.0f, e + 1.0f);
}

// ---------------------------------------------------------------------------
// fp32 -> bf16 conversion
// ---------------------------------------------------------------------------
__global__ void k_cvt(const float* __restrict__ in, __bf16* __restrict__ out, int n4) {
    int i = blockIdx.x * blockDim.x + threadIdx.x;
    if (i < n4) {
        float4 v = ((const float4*)in)[i];
        bf16x4 o;
        o[0] = (__bf16)v.x; o[1] = (__bf16)v.y; o[2] = (__bf16)v.z; o[3] = (__bf16)v.w;
        ((bf16x4*)out)[i] = o;
    }
}

// ---------------------------------------------------------------------------
// query[b, o] = tanh(dec_state[b,:] . Wq[o,:] + bq[o]);  one wave per output
// ---------------------------------------------------------------------------
__global__ void k_query(const float* __restrict__ dec, const float* __restrict__ Wq,
                        const float* __restrict__ bq, float* __restrict__ query) {
    int w = (blockIdx.x * blockDim.x + threadIdx.x) >> 6;
    int lane = threadIdx.x & 63;
    int b = w >> 11;
    int o = w & 2047;
    const float* dr = dec + b * QDIM;
    const float* wr = Wq + o * QDIM;
    float s = 0.f;
    #pragma unroll
    for (int i = 0; i < QDIM / 64; ++i) s = fmaf(dr[lane + 64 * i], wr[lane + 64 * i], s);
    #pragma unroll
    for (int off = 32; off > 0; off >>= 1) s += __shfl_down(s, off);
    if (lane == 0) query[b * NHD + o] = tanhf(s + bq[o]);
}

// ---------------------------------------------------------------------------
// Qtab[j,d] = sum_k proj[d,k] * P[k,j], P[k,j] = sum_{dt<j} sum_h convw[k,h,dt]
// ---------------------------------------------------------------------------
__global__ void k_qtab(const float* __restrict__ convw, const float* __restrict__ projw,
                       float* __restrict__ Qtab) {
    int j = blockIdx.x;       // 0..201
    __shared__ float P[KN];
    int tid = threadIdx.x;    // 512
    if (tid < KN) {
        const float* wr = convw + tid * (NH * (2 * KS + 1));
        float s = 0.f;
        for (int dt = 0; dt < j; ++dt)
            s += wr[dt] + wr[201 + dt] + wr[402 + dt] + wr[603 + dt];
        P[tid] = s;
    }
    __syncthreads();
    const float* pr = projw + tid * KN;
    float s = 0.f;
    #pragma unroll 4
    for (int k = 0; k < KN; ++k) s = fmaf(pr[k], P[k], s);
    Qtab[j * DIM + tid] = s;
}

// ---------------------------------------------------------------------------
// locI[b,d] = tanh((Qtab[2KS+1,d]-Qtab[0,d])/len_b) : the loc value for all
// interior t (KS <= t <= len-1-KS).
// ---------------------------------------------------------------------------
__global__ void k_locI(const float* __restrict__ Qtab, const int* __restrict__ enc_len,
                       float* __restrict__ locI) {
    int idx = blockIdx.x * blockDim.x + threadIdx.x;   // BS*DIM
    int b = idx >> 9, d = idx & (DIM - 1);
    float inv_len = 1.0f / (float)enc_len[b];
    locI[idx] = fast_tanh((Qtab[(2 * KS + 1) * DIM + d] - Qtab[d]) * inv_len);
}

// ===========================================================================
// MFMA GEMM core: 128x128 tile, BK=64, 256 thr, XOR-swizzled LDS (see R2)
// ===========================================================================
#define STAGE_TILE(dst, base)                                                     \
    {                                                                             \
        _Pragma("unroll")                                                         \
        for (int q = 0; q < 4; ++q) {                                             \
            int slotbase = (w * 4 + q) * 64;                                      \
            int m = (slotbase + lane) >> 3;                                       \
            int c = (lane & 7) ^ (lane >> 3);                                     \
            const __bf16* gp = (base) + (size_t)m * VDIM + k0 + c * 8;            \
            __builtin_amdgcn_global_load_lds(AS1(gp), AS3(dst + slotbase * 8),    \
                                             16, 0, 0);                           \
        }                                                                         \
    }

#define GEMM_MAIN(Bglobal, EARLY)                                                 \
    const int t0 = blockIdx.x * 128;                                              \
    const int n0 = blockIdx.y * 128;                                              \
    const int b  = blockIdx.z;                                                    \
    EARLY                                                                         \
    const int tid = threadIdx.x;                                                  \
    const int w = tid >> 6, lane = tid & 63;                                      \
    const int wy = w >> 1, wx = w & 1;                                            \
    const int col = lane & 15, quad = lane >> 4;                                  \
    __shared__ __bf16 Ash[128 * 64];                                              \
    __shared__ __bf16 Bsh[128 * 64];                                              \
    f32x4 acc[4][4];                                                              \
    _Pragma("unroll")                                                             \
    for (int i = 0; i < 4; ++i)                                                   \
        _Pragma("unroll")                                                         \
        for (int j = 0; j < 4; ++j) acc[i][j] = (f32x4)0.f;                       \
    const __bf16* Abase = enc_bf + ((size_t)b * TS + t0) * VDIM;                  \
    const __bf16* Bbase = (Bglobal) + (size_t)n0 * VDIM;                          \
    for (int k0 = 0; k0 < VDIM; k0 += 64) {                                       \
        STAGE_TILE(Ash, Abase)                                                    \
        STAGE_TILE(Bsh, Bbase)                                                    \
        __syncthreads();                                                          \
        _Pragma("unroll")                                                         \
        for (int ks = 0; ks < 2; ++ks) {                                          \
            bf16x8 af[4], bf[4];                                                  \
            int jslot = ((ks * 4 + quad) ^ (col & 7));                            \
            _Pragma("unroll")                                                     \
            for (int i = 0; i < 4; ++i) {                                         \
                int m = wy * 64 + i * 16 + col;                                   \
                af[i] = *(const bf16x8*)(Ash + (m * 8 + jslot) * 8);              \
            }                                                                     \
            _Pragma("unroll")                                                     \
            for (int j = 0; j < 4; ++j) {                                         \
                int n = wx * 64 + j * 16 + col;                                   \
                bf[j] = *(const bf16x8*)(Bsh + (n * 8 + jslot) * 8);              \
            }                                                                     \
            _Pragma("unroll")                                                     \
            for (int i = 0; i < 4; ++i)                                           \
                _Pragma("unroll")                                                 \
                for (int j = 0; j < 4; ++j)                                       \
                    acc[i][j] = __builtin_amdgcn_mfma_f32_16x16x32_bf16(          \
                        af[i], bf[j], acc[i][j], 0, 0, 0);                        \
        }                                                                         \
        __syncthreads();                                                          \
    }
// acc[i][j][r] = C[t0+wy*64+i*16+quad*4+r][n0+wx*64+j*16+col]

// ---------------------------------------------------------------------------
// Energy pass: C = enc @ Wk^T, epilogue:
//   energy[b,h,t] += sum_n tanh(tanh(C+bk)+query+loc) * gen_w[d]
// ---------------------------------------------------------------------------
__global__ __launch_bounds__(256) void k_energy(
    const __bf16* __restrict__ enc_bf, const __bf16* __restrict__ wk_bf,
    const float* __restrict__ bk, const float* __restrict__ gen_w,
    const int* __restrict__ enc_len, const float* __restrict__ query,
    const float* __restrict__ Qtab, const float* __restrict__ locI,
    float* __restrict__ energy) {
    GEMM_MAIN(wk_bf, const int len = enc_len[b]; if (t0 >= len) return;)

    const int h = n0 >> 9;
    const float inv_len = 1.0f / (float)len;
    float qv[4], gw[4], bkv[4], lI[4];
    int dj[4];
    #pragma unroll
    for (int j = 0; j < 4; ++j) {
        int n = n0 + wx * 64 + j * 16 + col;
        dj[j] = n & (DIM - 1);
        qv[j] = query[b * NHD + n];
        gw[j] = gen_w[dj[j]];
        bkv[j] = bk[n];
        lI[j] = locI[b * DIM + dj[j]];
    }
    #pragma unroll
    for (int i = 0; i < 4; ++i) {
        #pragma unroll
        for (int r = 0; r < 4; ++r) {
            int t = t0 + wy * 64 + i * 16 + quad * 4 + r;
            float l[4];
            if (t >= KS && t < len - KS) {           // interior: loc const in t
                #pragma unroll
                for (int j = 0; j < 4; ++j) l[j] = lI[j];
            } else {
                int lo = KS - t; if (lo < 0) lo = 0;
                int hi = KS - t + len - 1; if (hi > 2 * KS) hi = 2 * KS;
                bool has = (hi >= lo);
                #pragma unroll
                for (int j = 0; j < 4; ++j) {
                    float cv = has
                        ? (Qtab[(hi + 1) * DIM + dj[j]] - Qtab[lo * DIM + dj[j]]) * inv_len
                        : 0.f;
                    l[j] = fast_tanh(cv);
                }
            }
            float s = 0.f;
            #pragma unroll
            for (int j = 0; j < 4; ++j) {
                float key = fast_tanh(acc[i][j][r] + bkv[j]);
                float e = fast_tanh(key + qv[j] + l[j]);
                s = fmaf(e, gw[j], s);
            }
            s += __shfl_xor(s, 1); s += __shfl_xor(s, 2);
            s += __shfl_xor(s, 4); s += __shfl_xor(s, 8);
            if (col == 0) atomicAdd(&energy[(size_t)(b * NH + h) * TS + t], s);
        }
    }
}

// ---------------------------------------------------------------------------
// softmax over t (masked), writes attn to d_out[0 : 8*4*2048]
// ---------------------------------------------------------------------------
__global__ void k_softmax(const float* __restrict__ energy, const int* __restrict__ enc_len,
                          const float* __restrict__ gen_b, float* __restrict__ attn) {
    int bh = blockIdx.x;
    int b = bh >> 2;
    int len = enc_len[b];
    int tid = threadIdx.x;        // 256
    const float gb = gen_b[0];
    float ev[8];
    float mx = -INFINITY;
    #pragma unroll
    for (int i = 0; i < 8; ++i) {
        int t = i * 256 + tid;
        float e = (t < len) ? (energy[(size_t)bh * TS + t] + gb) * (1.0f / TEMPERATURE)
                            : -INFINITY;
        ev[i] = e;
        mx = fmaxf(mx, e);
    }
    __shared__ float sred[256];
    sred[tid] = mx; __syncthreads();
    for (int off = 128; off > 0; off >>= 1) {
        if (tid < off) sred[tid] = fmaxf(sred[tid], sred[tid + off]);
        __syncthreads();
    }
    mx = sred[0]; __syncthreads();
    float ls = 0.f;
    #pragma unroll
    for (int i = 0; i < 8; ++i) {
        float ex = __expf(ev[i] - mx);    // -inf -> 0
        ev[i] = ex;
        ls += ex;
    }
    sred[tid] = ls; __syncthreads();
    for (int off = 128; off > 0; off >>= 1) {
        if (tid < off) sred[tid] += sred[tid + off];
        __syncthreads();
    }
    float inv = 1.0f / sred[0];
    #pragma unroll
    for (int i = 0; i < 8; ++i)
        attn[(size_t)bh * TS + i * 256 + tid] = ev[i] * inv;
}

// ---------------------------------------------------------------------------
// ctx pass: C = enc @ Wv^T, epilogue: ctx[b,n] += sum_t attn * tanh(C + bv)
// ---------------------------------------------------------------------------
__global__ __launch_bounds__(256) void k_ctx(
    const __bf16* __restrict__ enc_bf, const __bf16* __restrict__ wv_bf,
    const float* __restrict__ bv, const float* __restrict__ attn,
    const int* __restrict__ enc_len, float* __restrict__ ctx) {
    GEMM_MAIN(wv_bf, const int len = enc_len[b]; if (t0 >= len) return;)

    const int h = n0 >> 9;
    float att[4][4];
    #pragma unroll
    for (int i = 0; i < 4; ++i)
        #pragma unroll
        for (int r = 0; r < 4; ++r)
            att[i][r] = attn[(size_t)(b * NH + h) * TS + t0 + wy * 64 + i * 16 + quad * 4 + r];
    #pragma unroll
    for (int j = 0; j < 4; ++j) {
        int n = n0 + wx * 64 + j * 16 + col;
        float bvn = bv[n];
        float s = 0.f;
        #pragma unroll
        for (int i = 0; i < 4; ++i)
            #pragma unroll
            for (int r = 0; r < 4; ++r)
                s = fmaf(att[i][r], fast_tanh(acc[i][j][r] + bvn), s);
        s += __shfl_xor(s, 16); s += __shfl_xor(s, 32);
        if (quad == 0) atomicAdd(&ctx[(size_t)b * NHD + n], s);
    }
}

// ---------------------------------------------------------------------------
// context[b,o] = ctx[b,:] . merge_w[o,:] + merge_b[o];  one wave per output
// ---------------------------------------------------------------------------
__global__ void k_merge(const float* __restrict__ ctx, const float* __restrict__ mw,
                        const float* __restrict__ mb, float* __restrict__ out) {
    int w = (blockIdx.x * blockDim.x + threadIdx.x) >> 6;
    int lane = threadIdx.x & 63;
    int b = w >> 9;
    int o = w & 511;
    const float* c = ctx + (size_t)b * NHD;
    const float* wr = mw + (size_t)o * NHD;
    float s = 0.f;
    #pragma unroll
    for (int i = 0; i < NHD / 64; ++i) s = fmaf(c[lane + 64 * i], wr[lane + 64 * i], s);
    #pragma unroll
    for (int off = 32; off > 0; off >>= 1) s += __shfl_down(s, off);
    if (lane == 0) out[b * VDIM + o] = s + mb[o];
}

extern "C" void kernel_launch(void* const* d_in, const int* in_sizes, int n_in,
                              void* d_out, int out_size, void* d_ws, size_t ws_size,
                              hipStream_t stream) {
    const float* dec     = (const float*)d_in[0];
    const float* enc     = (const float*)d_in[1];
    const int*   enc_len = (const int*)d_in[2];
    const float* Wq      = (const float*)d_in[3];
    const float* bq      = (const float*)d_in[4];
    const float* Wk      = (const float*)d_in[5];
    const float* bk      = (const float*)d_in[6];
    const float* Wv      = (const float*)d_in[7];
    const float* bv      = (const float*)d_in[8];
    const float* convw   = (const float*)d_in[9];
    const float* projw   = (const float*)d_in[10];
    const float* gen_w   = (const float*)d_in[11];
    const float* gen_b   = (const float*)d_in[12];
    const float* merge_w = (const float*)d_in[13];
    const float* merge_b = (const float*)d_in[14];

    float* out   = (float*)d_out;               // attn [65536] ++ context [4096]
    float* ws    = (float*)d_ws;
    float* query = ws + WS_QUERY;
    float* Qtab  = ws + WS_QTAB;
    float* energy= ws + WS_ENERGY;
    float* ctx   = ws + WS_CTX;
    float* locI  = ws + WS_LOCI;
    __bf16* enc_bf = (__bf16*)((char*)d_ws + (size_t)WS_F32_END * 4);
    __bf16* wk_bf  = enc_bf + (size_t)BS * TS * VDIM;
    __bf16* wv_bf  = wk_bf + (size_t)NHD * VDIM;

    // zero atomic accumulators (energy + ctx contiguous)
    hipMemsetAsync(energy, 0, (65536 + 16384) * sizeof(float), stream);

    k_cvt<<<dim3((BS * TS * VDIM / 4 + 255) / 256), dim3(256), 0, stream>>>(
        enc, enc_bf, BS * TS * VDIM / 4);
    k_cvt<<<dim3((NHD * VDIM / 4 + 255) / 256), dim3(256), 0, stream>>>(
        Wk, wk_bf, NHD * VDIM / 4);
    k_cvt<<<dim3((NHD * VDIM / 4 + 255) / 256), dim3(256), 0, stream>>>(
        Wv, wv_bf, NHD * VDIM / 4);
    k_query<<<dim3(BS * NHD / 4), dim3(256), 0, stream>>>(dec, Wq, bq, query);
    k_qtab<<<dim3(2 * KS + 2), dim3(512), 0, stream>>>(convw, projw, Qtab);
    k_locI<<<dim3(BS * DIM / 256), dim3(256), 0, stream>>>(Qtab, enc_len, locI);
    k_energy<<<dim3(TS / 128, NHD / 128, BS), dim3(256), 0, stream>>>(
        enc_bf, wk_bf, bk, gen_w, enc_len, query, Qtab, locI, energy);
    k_softmax<<<dim3(BS * NH), dim3(256), 0, stream>>>(energy, enc_len, gen_b, out);
    k_ctx<<<dim3(TS / 128, NHD / 128, BS), dim3(256), 0, stream>>>(
        enc_bf, wv_bf, bv, out, enc_len, ctx);
    k_merge<<<dim3(BS * VDIM / 4), dim3(256), 0, stream>>>(ctx, merge_w, merge_b, out + 65536);
}

// Round 4
// 367.221 us; speedup vs baseline: 3.8176x; 1.1635x over previous
//
#include <hip/hip_runtime.h>
#include <math.h>

#define NH 4
#define DIM 512
#define VDIM 512
#define QDIM 1024
#define KS 100
#define KN 100
#define TEMPERATURE 0.5f
#define BS 8
#define TS 2048
#define NHD (NH * DIM)          // 2048

// workspace layout (floats)
#define WS_QUERY  0                       // 16384
#define WS_QTAB   16384                   // 202*512 = 103424
#define WS_ENERGY 119808                  // 65536
#define WS_CTX    185344                  // 16384
#define WS_LOCI   201728                  // 8*512 = 4096
#define WS_F32_END 205824                 // -> 823296 bytes (16B aligned)
// bf16 region: enc_bf [8388608], wk_bf [1048576], wv_bf [1048576]

typedef __bf16 bf16x8 __attribute__((ext_vector_type(8)));
typedef __bf16 bf16x4 __attribute__((ext_vector_type(4)));
typedef float  f32x4  __attribute__((ext_vector_type(4)));

#define AS1(p) ((const __attribute__((address_space(1))) void*)(p))
#define AS3(p) ((__attribute__((address_space(3))) void*)(p))

// tanh(x) = (e-1)/(e+1), e = exp(2x); clamp so e never overflows.
__device__ __forceinline__ float fast_tanh(float x) {
    float xc = fminf(fmaxf(x, -9.0f), 9.0f);
    float e = __expf(2.0f * xc);
    return __fdividef(e - 1.0f, e + 1.0f);
}

// ---------------------------------------------------------------------------
// fp32 -> bf16 conversion, all three tensors in one launch
// ---------------------------------------------------------------------------
#define NE4 (BS * TS * VDIM / 4)      // 2097152
#define NW4 (NHD * VDIM / 4)          // 262144
__global__ void k_cvt3(const float* __restrict__ enc, const float* __restrict__ Wk,
                       const float* __restrict__ Wv, __bf16* __restrict__ enc_bf,
                       __bf16* __restrict__ wk_bf, __bf16* __restrict__ wv_bf) {
    int i = blockIdx.x * blockDim.x + threadIdx.x;
    const float* src; __bf16* dst; int k;
    if (i < NE4)                { src = enc; dst = enc_bf; k = i; }
    else if (i < NE4 + NW4)     { src = Wk;  dst = wk_bf;  k = i - NE4; }
    else                        { src = Wv;  dst = wv_bf;  k = i - NE4 - NW4; }
    float4 v = ((const float4*)src)[k];
    bf16x4 o;
    o[0] = (__bf16)v.x; o[1] = (__bf16)v.y; o[2] = (__bf16)v.z; o[3] = (__bf16)v.w;
    ((bf16x4*)dst)[k] = o;
}

// ---------------------------------------------------------------------------
// query[b, o] = tanh(dec_state[b,:] . Wq[o,:] + bq[o]);  one wave per output
// ---------------------------------------------------------------------------
__global__ void k_query(const float* __restrict__ dec, const float* __restrict__ Wq,
                        const float* __restrict__ bq, float* __restrict__ query) {
    int w = (blockIdx.x * blockDim.x + threadIdx.x) >> 6;
    int lane = threadIdx.x & 63;
    int b = w >> 11;
    int o = w & 2047;
    const float* dr = dec + b * QDIM;
    const float* wr = Wq + o * QDIM;
    float s = 0.f;
    #pragma unroll
    for (int i = 0; i < QDIM / 64; ++i) s = fmaf(dr[lane + 64 * i], wr[lane + 64 * i], s);
    #pragma unroll
    for (int off = 32; off > 0; off >>= 1) s += __shfl_down(s, off);
    if (lane == 0) query[b * NHD + o] = tanhf(s + bq[o]);
}

// ---------------------------------------------------------------------------
// Qtab[j,d] = sum_k proj[d,k] * P[k,j], P[k,j] = sum_{dt<j} sum_h convw[k,h,dt]
// ---------------------------------------------------------------------------
__global__ void k_qtab(const float* __restrict__ convw, const float* __restrict__ projw,
                       float* __restrict__ Qtab) {
    int j = blockIdx.x;       // 0..201
    __shared__ float P[KN];
    int tid = threadIdx.x;    // 512
    if (tid < KN) {
        const float* wr = convw + tid * (NH * (2 * KS + 1));
        float s = 0.f;
        for (int dt = 0; dt < j; ++dt)
            s += wr[dt] + wr[201 + dt] + wr[402 + dt] + wr[603 + dt];
        P[tid] = s;
    }
    __syncthreads();
    const float* pr = projw + tid * KN;
    float s = 0.f;
    #pragma unroll 4
    for (int k = 0; k < KN; ++k) s = fmaf(pr[k], P[k], s);
    Qtab[j * DIM + tid] = s;
}

// ---------------------------------------------------------------------------
// locI[b,d] = tanh((Qtab[2KS+1,d]-Qtab[0,d])/len_b)  (interior-t loc value)
// ---------------------------------------------------------------------------
__global__ void k_locI(const float* __restrict__ Qtab, const int* __restrict__ enc_len,
                       float* __restrict__ locI) {
    int idx = blockIdx.x * blockDim.x + threadIdx.x;   // BS*DIM
    int b = idx >> 9, d = idx & (DIM - 1);
    float inv_len = 1.0f / (float)enc_len[b];
    locI[idx] = fast_tanh((Qtab[(2 * KS + 1) * DIM + d] - Qtab[d]) * inv_len);
}

// ===========================================================================
// MFMA GEMM core: 128x128 tile, BK=64, 512 threads (8 waves, 2x4 grid,
// wave tile 64x32 -> acc 32 regs), double-buffered LDS, ONE barrier/iter:
//   barrier; issue loads for tile k+1; compute tile k   (latency hidden)
// XOR-swizzled LDS slots: slot(m,j) holds chunk c=j^(m&7) -> coalesced
// global_load_lds + 2-way-free ds_read_b128.
// ===========================================================================
#define STAGE2(AshB, BshB, k0)                                                    \
    {                                                                             \
        int cch = (lane & 7) ^ (lane >> 3);                                       \
        _Pragma("unroll")                                                         \
        for (int q = 0; q < 2; ++q) {                                             \
            int slotbase = (w * 2 + q) * 64;                                      \
            int m = (slotbase >> 3) + (lane >> 3);                                \
            __builtin_amdgcn_global_load_lds(                                     \
                AS1(Abase + (size_t)m * VDIM + (k0) + cch * 8),                   \
                AS3((AshB) + slotbase * 8), 16, 0, 0);                            \
            __builtin_amdgcn_global_load_lds(                                     \
                AS1(Bbase + (size_t)m * VDIM + (k0) + cch * 8),                   \
                AS3((BshB) + slotbase * 8), 16, 0, 0);                            \
        }                                                                         \
    }

#define GEMM_MAIN(Bglobal, EARLY)                                                 \
    const int t0 = blockIdx.x * 128;                                              \
    const int n0 = blockIdx.y * 128;                                              \
    const int b  = blockIdx.z;                                                    \
    EARLY                                                                         \
    const int tid = threadIdx.x;                                                  \
    const int w = tid >> 6, lane = tid & 63;                                      \
    const int wy = w >> 2, wx = w & 3;                                            \
    const int col = lane & 15, quad = lane >> 4;                                  \
    __shared__ __bf16 Ash[2][128 * 64];                                           \
    __shared__ __bf16 Bsh[2][128 * 64];                                           \
    f32x4 acc[4][2];                                                              \
    _Pragma("unroll")                                                             \
    for (int i = 0; i < 4; ++i)                                                   \
        _Pragma("unroll")                                                         \
        for (int j = 0; j < 2; ++j) acc[i][j] = (f32x4)0.f;                       \
    const __bf16* Abase = enc_bf + ((size_t)b * TS + t0) * VDIM;                  \
    const __bf16* Bbase = (Bglobal) + (size_t)n0 * VDIM;                          \
    STAGE2(Ash[0], Bsh[0], 0)                                                     \
    for (int kk = 0; kk < 8; ++kk) {                                              \
        __syncthreads();                                                          \
        if (kk < 7) STAGE2(Ash[(kk + 1) & 1], Bsh[(kk + 1) & 1], (kk + 1) * 64)   \
        const __bf16* As = Ash[kk & 1];                                           \
        const __bf16* Bs = Bsh[kk & 1];                                           \
        _Pragma("unroll")                                                         \
        for (int ks = 0; ks < 2; ++ks) {                                          \
            bf16x8 af[4], bfr[2];                                                 \
            int jslot = ((ks * 4 + quad) ^ (col & 7));                            \
            _Pragma("unroll")                                                     \
            for (int i = 0; i < 4; ++i) {                                         \
                int m = wy * 64 + i * 16 + col;                                   \
                af[i] = *(const bf16x8*)(As + (m * 8 + jslot) * 8);               \
            }                                                                     \
            _Pragma("unroll")                                                     \
            for (int j = 0; j < 2; ++j) {                                         \
                int n = wx * 32 + j * 16 + col;                                   \
                bfr[j] = *(const bf16x8*)(Bs + (n * 8 + jslot) * 8);              \
            }                                                                     \
            _Pragma("unroll")                                                     \
            for (int i = 0; i < 4; ++i)                                           \
                _Pragma("unroll")                                                 \
                for (int j = 0; j < 2; ++j)                                       \
                    acc[i][j] = __builtin_amdgcn_mfma_f32_16x16x32_bf16(          \
                        af[i], bfr[j], acc[i][j], 0, 0, 0);                       \
        }                                                                         \
    }                                                                             \
    __syncthreads();
// acc[i][j][r] = C[t0+wy*64+i*16+quad*4+r][n0+wx*32+j*16+col]

// ---------------------------------------------------------------------------
// Energy pass: C = enc @ Wk^T, epilogue:
//   energy[b,h,t] += sum_n tanh(tanh(C+bk)+query+loc) * gen_w[d]
// ---------------------------------------------------------------------------
__global__ __launch_bounds__(512, 4) void k_energy(
    const __bf16* __restrict__ enc_bf, const __bf16* __restrict__ wk_bf,
    const float* __restrict__ bk, const float* __restrict__ gen_w,
    const int* __restrict__ enc_len, const float* __restrict__ query,
    const float* __restrict__ Qtab, const float* __restrict__ locI,
    float* __restrict__ energy) {
    GEMM_MAIN(wk_bf, const int len = enc_len[b]; if (t0 >= len) return;)

    const int h = n0 >> 9;
    const float inv_len = 1.0f / (float)len;
    float qv[2], gw[2], bkv[2], lI[2];
    int dj[2];
    #pragma unroll
    for (int j = 0; j < 2; ++j) {
        int n = n0 + wx * 32 + j * 16 + col;
        dj[j] = n & (DIM - 1);
        qv[j] = query[b * NHD + n];
        gw[j] = gen_w[dj[j]];
        bkv[j] = bk[n];
        lI[j] = locI[b * DIM + dj[j]];
    }
    float* red = (float*)Ash;   // [128][4]
    #pragma unroll
    for (int i = 0; i < 4; ++i) {
        #pragma unroll
        for (int r = 0; r < 4; ++r) {
            int tl = wy * 64 + i * 16 + quad * 4 + r;
            int t = t0 + tl;
            float l[2];
            if (t >= KS && t < len - KS) {           // interior: loc const in t
                #pragma unroll
                for (int j = 0; j < 2; ++j) l[j] = lI[j];
            } else {
                int lo = KS - t; if (lo < 0) lo = 0;
                int hi = KS - t + len - 1; if (hi > 2 * KS) hi = 2 * KS;
                bool has = (hi >= lo);
                #pragma unroll
                for (int j = 0; j < 2; ++j) {
                    float cv = has
                        ? (Qtab[(hi + 1) * DIM + dj[j]] - Qtab[lo * DIM + dj[j]]) * inv_len
                        : 0.f;
                    l[j] = fast_tanh(cv);
                }
            }
            float s = 0.f;
            #pragma unroll
            for (int j = 0; j < 2; ++j) {
                float key = fast_tanh(acc[i][j][r] + bkv[j]);
                float e = fast_tanh(key + qv[j] + l[j]);
                s = fmaf(e, gw[j], s);
            }
            s += __shfl_xor(s, 1); s += __shfl_xor(s, 2);
            s += __shfl_xor(s, 4); s += __shfl_xor(s, 8);
            if (col == 0) red[tl * 4 + wx] = s;
        }
    }
    __syncthreads();
    if (tid < 128) {
        float s = red[tid * 4] + red[tid * 4 + 1] + red[tid * 4 + 2] + red[tid * 4 + 3];
        atomicAdd(&energy[(size_t)(b * NH + h) * TS + t0 + tid], s);
    }
}

// ---------------------------------------------------------------------------
// softmax over t (masked), shuffle-based, writes attn to d_out
// ---------------------------------------------------------------------------
__global__ void k_softmax(const float* __restrict__ energy, const int* __restrict__ enc_len,
                          const float* __restrict__ gen_b, float* __restrict__ attn) {
    int bh = blockIdx.x;          // 32
    int b = bh >> 2;
    int len = enc_len[b];
    int tid = threadIdx.x;        // 512
    int w = tid >> 6, lane = tid & 63;
    const float gb = gen_b[0];
    float ev[4];
    float mx = -INFINITY;
    #pragma unroll
    for (int i = 0; i < 4; ++i) {
        int t = i * 512 + tid;
        float e = (t < len) ? (energy[(size_t)bh * TS + t] + gb) * (1.0f / TEMPERATURE)
                            : -INFINITY;
        ev[i] = e;
        mx = fmaxf(mx, e);
    }
    __shared__ float sred[8], ssum[8];
    #pragma unroll
    for (int off = 32; off > 0; off >>= 1) mx = fmaxf(mx, __shfl_xor(mx, off));
    if (lane == 0) sred[w] = mx;
    __syncthreads();
    #pragma unroll
    for (int k = 0; k < 8; ++k) mx = fmaxf(mx, sred[k]);
    float ls = 0.f;
    #pragma unroll
    for (int i = 0; i < 4; ++i) {
        float ex = __expf(ev[i] - mx);    // -inf -> 0
        ev[i] = ex;
        ls += ex;
    }
    #pragma unroll
    for (int off = 32; off > 0; off >>= 1) ls += __shfl_xor(ls, off);
    if (lane == 0) ssum[w] = ls;
    __syncthreads();
    float tot = 0.f;
    #pragma unroll
    for (int k = 0; k < 8; ++k) tot += ssum[k];
    float inv = 1.0f / tot;
    #pragma unroll
    for (int i = 0; i < 4; ++i)
        attn[(size_t)bh * TS + i * 512 + tid] = ev[i] * inv;
}

// ---------------------------------------------------------------------------
// ctx pass: C = enc @ Wv^T, epilogue: ctx[b,n] += sum_t attn * tanh(C + bv)
// ---------------------------------------------------------------------------
__global__ __launch_bounds__(512, 4) void k_ctx(
    const __bf16* __restrict__ enc_bf, const __bf16* __restrict__ wv_bf,
    const float* __restrict__ bv, const float* __restrict__ attn,
    const int* __restrict__ enc_len, float* __restrict__ ctx) {
    GEMM_MAIN(wv_bf, const int len = enc_len[b]; if (t0 >= len) return;)

    const int h = n0 >> 9;
    float att[4][4];
    #pragma unroll
    for (int i = 0; i < 4; ++i)
        #pragma unroll
        for (int r = 0; r < 4; ++r)
            att[i][r] = attn[(size_t)(b * NH + h) * TS + t0 + wy * 64 + i * 16 + quad * 4 + r];
    float* red = (float*)Ash;   // [128][2]
    #pragma unroll
    for (int j = 0; j < 2; ++j) {
        int nl = wx * 32 + j * 16 + col;
        float bvn = bv[n0 + nl];
        float s = 0.f;
        #pragma unroll
        for (int i = 0; i < 4; ++i)
            #pragma unroll
            for (int r = 0; r < 4; ++r)
                s = fmaf(att[i][r], fast_tanh(acc[i][j][r] + bvn), s);
        s += __shfl_xor(s, 16); s += __shfl_xor(s, 32);
        if (quad == 0) red[nl * 2 + wy] = s;
    }
    __syncthreads();
    if (tid < 128) {
        float s = red[tid * 2] + red[tid * 2 + 1];
        atomicAdd(&ctx[(size_t)b * NHD + n0 + tid], s);
    }
}

// ---------------------------------------------------------------------------
// context[b,o] = ctx[b,:] . merge_w[o,:] + merge_b[o];  one wave per output
// ---------------------------------------------------------------------------
__global__ void k_merge(const float* __restrict__ ctx, const float* __restrict__ mw,
                        const float* __restrict__ mb, float* __restrict__ out) {
    int w = (blockIdx.x * blockDim.x + threadIdx.x) >> 6;
    int lane = threadIdx.x & 63;
    int b = w >> 9;
    int o = w & 511;
    const float* c = ctx + (size_t)b * NHD;
    const float* wr = mw + (size_t)o * NHD;
    float s = 0.f;
    #pragma unroll
    for (int i = 0; i < NHD / 64; ++i) s = fmaf(c[lane + 64 * i], wr[lane + 64 * i], s);
    #pragma unroll
    for (int off = 32; off > 0; off >>= 1) s += __shfl_down(s, off);
    if (lane == 0) out[b * VDIM + o] = s + mb[o];
}

extern "C" void kernel_launch(void* const* d_in, const int* in_sizes, int n_in,
                              void* d_out, int out_size, void* d_ws, size_t ws_size,
                              hipStream_t stream) {
    const float* dec     = (const float*)d_in[0];
    const float* enc     = (const float*)d_in[1];
    const int*   enc_len = (const int*)d_in[2];
    const float* Wq      = (const float*)d_in[3];
    const float* bq      = (const float*)d_in[4];
    const float* Wk      = (const float*)d_in[5];
    const float* bk      = (const float*)d_in[6];
    const float* Wv      = (const float*)d_in[7];
    const float* bv      = (const float*)d_in[8];
    const float* convw   = (const float*)d_in[9];
    const float* projw   = (const float*)d_in[10];
    const float* gen_w   = (const float*)d_in[11];
    const float* gen_b   = (const float*)d_in[12];
    const float* merge_w = (const float*)d_in[13];
    const float* merge_b = (const float*)d_in[14];

    float* out   = (float*)d_out;               // attn [65536] ++ context [4096]
    float* ws    = (float*)d_ws;
    float* query = ws + WS_QUERY;
    float* Qtab  = ws + WS_QTAB;
    float* energy= ws + WS_ENERGY;
    float* ctx   = ws + WS_CTX;
    float* locI  = ws + WS_LOCI;
    __bf16* enc_bf = (__bf16*)((char*)d_ws + (size_t)WS_F32_END * 4);
    __bf16* wk_bf  = enc_bf + (size_t)BS * TS * VDIM;
    __bf16* wv_bf  = wk_bf + (size_t)NHD * VDIM;

    // zero atomic accumulators (energy + ctx contiguous)
    hipMemsetAsync(energy, 0, (65536 + 16384) * sizeof(float), stream);

    k_cvt3<<<dim3((NE4 + 2 * NW4) / 256), dim3(256), 0, stream>>>(
        enc, Wk, Wv, enc_bf, wk_bf, wv_bf);
    k_query<<<dim3(BS * NHD / 4), dim3(256), 0, stream>>>(dec, Wq, bq, query);
    k_qtab<<<dim3(2 * KS + 2), dim3(512), 0, stream>>>(convw, projw, Qtab);
    k_locI<<<dim3(BS * DIM / 256), dim3(256), 0, stream>>>(Qtab, enc_len, locI);
    k_energy<<<dim3(TS / 128, NHD / 128, BS), dim3(512), 0, stream>>>(
        enc_bf, wk_bf, bk, gen_w, enc_len, query, Qtab, locI, energy);
    k_softmax<<<dim3(BS * NH), dim3(512), 0, stream>>>(energy, enc_len, gen_b, out);
    k_ctx<<<dim3(TS / 128, NHD / 128, BS), dim3(512), 0, stream>>>(
        enc_bf, wv_bf, bv, out, enc_len, ctx);
    k_merge<<<dim3(BS * VDIM / 4), dim3(256), 0, stream>>>(ctx, merge_w, merge_b, out + 65536);
}

// Round 5
// 348.114 us; speedup vs baseline: 4.0271x; 1.0549x over previous
//
#include <hip/hip_runtime.h>
#include <math.h>

#define NH 4
#define DIM 512
#define VDIM 512
#define QDIM 1024
#define KS 100
#define KN 100
#define TEMPERATURE 0.5f
#define BS 8
#define TS 2048
#define NHD (NH * DIM)          // 2048

// workspace layout (floats)
#define WS_QUERY  0                       // 16384
#define WS_QTAB   16384                   // 202*512 = 103424
#define WS_ENERGY 119808                  // 65536
#define WS_CTX    185344                  // 16384
#define WS_LOCI   201728                  // 8*512 = 4096
#define WS_P      205824                  // 202*100 = 20200
#define WS_F32_END 226028                 // pad to even -> 226028*4 bytes
// bf16 region: enc_bf [8388608], wk_bf [1048576], wv_bf [1048576]

typedef __bf16 bf16x8 __attribute__((ext_vector_type(8)));
typedef __bf16 bf16x4 __attribute__((ext_vector_type(4)));
typedef float  f32x4  __attribute__((ext_vector_type(4)));

#define AS1(p) ((const __attribute__((address_space(1))) void*)(p))
#define AS3(p) ((__attribute__((address_space(3))) void*)(p))

// tanh(x) = (e-1)/(e+1), e = exp(2x); clamp so e never overflows.
__device__ __forceinline__ float fast_tanh(float x) {
    float xc = fminf(fmaxf(x, -9.0f), 9.0f);
    float e = __expf(2.0f * xc);
    return __fdividef(e - 1.0f, e + 1.0f);
}

// ---------------------------------------------------------------------------
// fp32 -> bf16 conversion, all three tensors in one launch
// ---------------------------------------------------------------------------
#define NE4 (BS * TS * VDIM / 4)      // 2097152
#define NW4 (NHD * VDIM / 4)          // 262144
__global__ void k_cvt3(const float* __restrict__ enc, const float* __restrict__ Wk,
                       const float* __restrict__ Wv, __bf16* __restrict__ enc_bf,
                       __bf16* __restrict__ wk_bf, __bf16* __restrict__ wv_bf) {
    int i = blockIdx.x * blockDim.x + threadIdx.x;
    const float* src; __bf16* dst; int k;
    if (i < NE4)                { src = enc; dst = enc_bf; k = i; }
    else if (i < NE4 + NW4)     { src = Wk;  dst = wk_bf;  k = i - NE4; }
    else                        { src = Wv;  dst = wv_bf;  k = i - NE4 - NW4; }
    float4 v = ((const float4*)src)[k];
    bf16x4 o;
    o[0] = (__bf16)v.x; o[1] = (__bf16)v.y; o[2] = (__bf16)v.z; o[3] = (__bf16)v.w;
    ((bf16x4*)dst)[k] = o;
}

// ---------------------------------------------------------------------------
// query[b, o] = tanh(dec_state[b,:] . Wq[o,:] + bq[o]);  one wave per output
// ---------------------------------------------------------------------------
__global__ void k_query(const float* __restrict__ dec, const float* __restrict__ Wq,
                        const float* __restrict__ bq, float* __restrict__ query) {
    int w = (blockIdx.x * blockDim.x + threadIdx.x) >> 6;
    int lane = threadIdx.x & 63;
    int b = w >> 11;
    int o = w & 2047;
    const float* dr = dec + b * QDIM;
    const float* wr = Wq + o * QDIM;
    float s = 0.f;
    #pragma unroll
    for (int i = 0; i < QDIM / 64; ++i) s = fmaf(dr[lane + 64 * i], wr[lane + 64 * i], s);
    #pragma unroll
    for (int off = 32; off > 0; off >>= 1) s += __shfl_down(s, off);
    if (lane == 0) query[b * NHD + o] = tanhf(s + bq[o]);
}

// ---------------------------------------------------------------------------
// P[j][k] = sum_{dt<j} sum_h convw[k,h,dt]  -- one linear sweep per k.
// 1 block, 128 threads (k < 100 active); rows contiguous -> L1 resident.
// ---------------------------------------------------------------------------
__global__ void k_prefix(const float* __restrict__ convw, float* __restrict__ P) {
    int k = threadIdx.x;
    if (k >= KN) return;
    const float* wr = convw + k * (NH * (2 * KS + 1));
    float acc = 0.f;
    P[k] = 0.f;                        // j = 0
    for (int dt = 0; dt < 2 * KS + 1; ++dt) {
        acc += wr[dt] + wr[201 + dt] + wr[402 + dt] + wr[603 + dt];
        P[(dt + 1) * KN + k] = acc;    // j = dt+1
    }
}

// ---------------------------------------------------------------------------
// Qtab[j,d] = sum_k projw[d,k] * P[j,k]
// ---------------------------------------------------------------------------
__global__ void k_qtab(const float* __restrict__ P, const float* __restrict__ projw,
                       float* __restrict__ Qtab) {
    int j = blockIdx.x;       // 0..201
    __shared__ float Pc[KN];
    int tid = threadIdx.x;    // 512
    if (tid < KN) Pc[tid] = P[j * KN + tid];
    __syncthreads();
    const float* pr = projw + tid * KN;
    float s = 0.f;
    #pragma unroll 4
    for (int k = 0; k < KN; ++k) s = fmaf(pr[k], Pc[k], s);
    Qtab[j * DIM + tid] = s;
}

// ---------------------------------------------------------------------------
// locI[b,d] = tanh((Qtab[2KS+1,d]-Qtab[0,d])/len_b)  (interior-t loc value)
// ---------------------------------------------------------------------------
__global__ void k_locI(const float* __restrict__ Qtab, const int* __restrict__ enc_len,
                       float* __restrict__ locI) {
    int idx = blockIdx.x * blockDim.x + threadIdx.x;   // BS*DIM
    int b = idx >> 9, d = idx & (DIM - 1);
    float inv_len = 1.0f / (float)enc_len[b];
    locI[idx] = fast_tanh((Qtab[(2 * KS + 1) * DIM + d] - Qtab[d]) * inv_len);
}

// ===========================================================================
// MFMA GEMM core: 128x128 tile, BK=64, 512 threads (8 waves, 2x4 grid,
// wave tile 64x32), double-buffered LDS, ONE barrier/iter.
// XOR-swizzled LDS slots: slot(m,j) holds chunk c=j^(m&7).
// ===========================================================================
#define STAGE2(AshB, BshB, k0)                                                    \
    {                                                                             \
        int cch = (lane & 7) ^ (lane >> 3);                                       \
        _Pragma("unroll")                                                         \
        for (int q = 0; q < 2; ++q) {                                             \
            int slotbase = (w * 2 + q) * 64;                                      \
            int m = (slotbase >> 3) + (lane >> 3);                                \
            __builtin_amdgcn_global_load_lds(                                     \
                AS1(Abase + (size_t)m * VDIM + (k0) + cch * 8),                   \
                AS3((AshB) + slotbase * 8), 16, 0, 0);                            \
            __builtin_amdgcn_global_load_lds(                                     \
                AS1(Bbase + (size_t)m * VDIM + (k0) + cch * 8),                   \
                AS3((BshB) + slotbase * 8), 16, 0, 0);                            \
        }                                                                         \
    }

#define GEMM_MAIN(Bglobal, EARLY)                                                 \
    const int t0 = blockIdx.x * 128;                                              \
    const int n0 = blockIdx.y * 128;                                              \
    const int b  = blockIdx.z;                                                    \
    EARLY                                                                         \
    const int tid = threadIdx.x;                                                  \
    const int w = tid >> 6, lane = tid & 63;                                      \
    const int wy = w >> 2, wx = w & 3;                                            \
    const int col = lane & 15, quad = lane >> 4;                                  \
    __shared__ __bf16 Ash[2][128 * 64];                                           \
    __shared__ __bf16 Bsh[2][128 * 64];                                           \
    f32x4 acc[4][2];                                                              \
    _Pragma("unroll")                                                             \
    for (int i = 0; i < 4; ++i)                                                   \
        _Pragma("unroll")                                                         \
        for (int j = 0; j < 2; ++j) acc[i][j] = (f32x4)0.f;                       \
    const __bf16* Abase = enc_bf + ((size_t)b * TS + t0) * VDIM;                  \
    const __bf16* Bbase = (Bglobal) + (size_t)n0 * VDIM;                          \
    STAGE2(Ash[0], Bsh[0], 0)                                                     \
    for (int kk = 0; kk < 8; ++kk) {                                              \
        __syncthreads();                                                          \
        if (kk < 7) STAGE2(Ash[(kk + 1) & 1], Bsh[(kk + 1) & 1], (kk + 1) * 64)   \
        const __bf16* As = Ash[kk & 1];                                           \
        const __bf16* Bs = Bsh[kk & 1];                                           \
        _Pragma("unroll")                                                         \
        for (int ks = 0; ks < 2; ++ks) {                                          \
            bf16x8 af[4], bfr[2];                                                 \
            int jslot = ((ks * 4 + quad) ^ (col & 7));                            \
            _Pragma("unroll")                                                     \
            for (int i = 0; i < 4; ++i) {                                         \
                int m = wy * 64 + i * 16 + col;                                   \
                af[i] = *(const bf16x8*)(As + (m * 8 + jslot) * 8);               \
            }                                                                     \
            _Pragma("unroll")                                                     \
            for (int j = 0; j < 2; ++j) {                                         \
                int n = wx * 32 + j * 16 + col;                                   \
                bfr[j] = *(const bf16x8*)(Bs + (n * 8 + jslot) * 8);              \
            }                                                                     \
            _Pragma("unroll")                                                     \
            for (int i = 0; i < 4; ++i)                                           \
                _Pragma("unroll")                                                 \
                for (int j = 0; j < 2; ++j)                                       \
                    acc[i][j] = __builtin_amdgcn_mfma_f32_16x16x32_bf16(          \
                        af[i], bfr[j], acc[i][j], 0, 0, 0);                       \
        }                                                                         \
    }                                                                             \
    __syncthreads();
// acc[i][j][r] = C[t0+wy*64+i*16+quad*4+r][n0+wx*32+j*16+col]

// ---------------------------------------------------------------------------
// Energy pass: C = enc @ Wk^T, epilogue:
//   energy[b,h,t] += sum_n tanh(tanh(C+bk)+query+loc) * gen_w[d]
// ---------------------------------------------------------------------------
__global__ __launch_bounds__(512, 4) void k_energy(
    const __bf16* __restrict__ enc_bf, const __bf16* __restrict__ wk_bf,
    const float* __restrict__ bk, const float* __restrict__ gen_w,
    const int* __restrict__ enc_len, const float* __restrict__ query,
    const float* __restrict__ Qtab, const float* __restrict__ locI,
    float* __restrict__ energy) {
    GEMM_MAIN(wk_bf, const int len = enc_len[b]; if (t0 >= len) return;)

    const int h = n0 >> 9;
    const float inv_len = 1.0f / (float)len;
    float qv[2], gw[2], bkv[2], lI[2];
    int dj[2];
    #pragma unroll
    for (int j = 0; j < 2; ++j) {
        int n = n0 + wx * 32 + j * 16 + col;
        dj[j] = n & (DIM - 1);
        qv[j] = query[b * NHD + n];
        gw[j] = gen_w[dj[j]];
        bkv[j] = bk[n];
        lI[j] = locI[b * DIM + dj[j]];
    }
    float* red = (float*)Ash;   // [128][4]
    #pragma unroll
    for (int i = 0; i < 4; ++i) {
        #pragma unroll
        for (int r = 0; r < 4; ++r) {
            int tl = wy * 64 + i * 16 + quad * 4 + r;
            int t = t0 + tl;
            float l[2];
            if (t >= KS && t < len - KS) {           // interior: loc const in t
                #pragma unroll
                for (int j = 0; j < 2; ++j) l[j] = lI[j];
            } else {
                int lo = KS - t; if (lo < 0) lo = 0;
                int hi = KS - t + len - 1; if (hi > 2 * KS) hi = 2 * KS;
                bool has = (hi >= lo);
                #pragma unroll
                for (int j = 0; j < 2; ++j) {
                    float cv = has
                        ? (Qtab[(hi + 1) * DIM + dj[j]] - Qtab[lo * DIM + dj[j]]) * inv_len
                        : 0.f;
                    l[j] = fast_tanh(cv);
                }
            }
            float s = 0.f;
            #pragma unroll
            for (int j = 0; j < 2; ++j) {
                float key = fast_tanh(acc[i][j][r] + bkv[j]);
                float e = fast_tanh(key + qv[j] + l[j]);
                s = fmaf(e, gw[j], s);
            }
            s += __shfl_xor(s, 1); s += __shfl_xor(s, 2);
            s += __shfl_xor(s, 4); s += __shfl_xor(s, 8);
            if (col == 0) red[tl * 4 + wx] = s;
        }
    }
    __syncthreads();
    if (tid < 128) {
        float s = red[tid * 4] + red[tid * 4 + 1] + red[tid * 4 + 2] + red[tid * 4 + 3];
        atomicAdd(&energy[(size_t)(b * NH + h) * TS + t0 + tid], s);
    }
}

// ---------------------------------------------------------------------------
// softmax over t (masked), shuffle-based, writes attn to d_out
// ---------------------------------------------------------------------------
__global__ void k_softmax(const float* __restrict__ energy, const int* __restrict__ enc_len,
                          const float* __restrict__ gen_b, float* __restrict__ attn) {
    int bh = blockIdx.x;          // 32
    int b = bh >> 2;
    int len = enc_len[b];
    int tid = threadIdx.x;        // 512
    int w = tid >> 6, lane = tid & 63;
    const float gb = gen_b[0];
    float ev[4];
    float mx = -INFINITY;
    #pragma unroll
    for (int i = 0; i < 4; ++i) {
        int t = i * 512 + tid;
        float e = (t < len) ? (energy[(size_t)bh * TS + t] + gb) * (1.0f / TEMPERATURE)
                            : -INFINITY;
        ev[i] = e;
        mx = fmaxf(mx, e);
    }
    __shared__ float sred[8], ssum[8];
    #pragma unroll
    for (int off = 32; off > 0; off >>= 1) mx = fmaxf(mx, __shfl_xor(mx, off));
    if (lane == 0) sred[w] = mx;
    __syncthreads();
    #pragma unroll
    for (int k = 0; k < 8; ++k) mx = fmaxf(mx, sred[k]);
    float ls = 0.f;
    #pragma unroll
    for (int i = 0; i < 4; ++i) {
        float ex = __expf(ev[i] - mx);    // -inf -> 0
        ev[i] = ex;
        ls += ex;
    }
    #pragma unroll
    for (int off = 32; off > 0; off >>= 1) ls += __shfl_xor(ls, off);
    if (lane == 0) ssum[w] = ls;
    __syncthreads();
    float tot = 0.f;
    #pragma unroll
    for (int k = 0; k < 8; ++k) tot += ssum[k];
    float inv = 1.0f / tot;
    #pragma unroll
    for (int i = 0; i < 4; ++i)
        attn[(size_t)bh * TS + i * 512 + tid] = ev[i] * inv;
}

// ---------------------------------------------------------------------------
// ctx pass: C = enc @ Wv^T, epilogue: ctx[b,n] += sum_t attn * tanh(C + bv)
// ---------------------------------------------------------------------------
__global__ __launch_bounds__(512, 4) void k_ctx(
    const __bf16* __restrict__ enc_bf, const __bf16* __restrict__ wv_bf,
    const float* __restrict__ bv, const float* __restrict__ attn,
    const int* __restrict__ enc_len, float* __restrict__ ctx) {
    GEMM_MAIN(wv_bf, const int len = enc_len[b]; if (t0 >= len) return;)

    const int h = n0 >> 9;
    float att[4][4];
    #pragma unroll
    for (int i = 0; i < 4; ++i)
        #pragma unroll
        for (int r = 0; r < 4; ++r)
            att[i][r] = attn[(size_t)(b * NH + h) * TS + t0 + wy * 64 + i * 16 + quad * 4 + r];
    float* red = (float*)Ash;   // [128][2]
    #pragma unroll
    for (int j = 0; j < 2; ++j) {
        int nl = wx * 32 + j * 16 + col;
        float bvn = bv[n0 + nl];
        float s = 0.f;
        #pragma unroll
        for (int i = 0; i < 4; ++i)
            #pragma unroll
            for (int r = 0; r < 4; ++r)
                s = fmaf(att[i][r], fast_tanh(acc[i][j][r] + bvn), s);
        s += __shfl_xor(s, 16); s += __shfl_xor(s, 32);
        if (quad == 0) red[nl * 2 + wy] = s;
    }
    __syncthreads();
    if (tid < 128) {
        float s = red[tid * 2] + red[tid * 2 + 1];
        atomicAdd(&ctx[(size_t)b * NHD + n0 + tid], s);
    }
}

// ---------------------------------------------------------------------------
// context[b,o] = ctx[b,:] . merge_w[o,:] + merge_b[o];  one wave per output
// ---------------------------------------------------------------------------
__global__ void k_merge(const float* __restrict__ ctx, const float* __restrict__ mw,
                        const float* __restrict__ mb, float* __restrict__ out) {
    int w = (blockIdx.x * blockDim.x + threadIdx.x) >> 6;
    int lane = threadIdx.x & 63;
    int b = w >> 9;
    int o = w & 511;
    const float* c = ctx + (size_t)b * NHD;
    const float* wr = mw + (size_t)o * NHD;
    float s = 0.f;
    #pragma unroll
    for (int i = 0; i < NHD / 64; ++i) s = fmaf(c[lane + 64 * i], wr[lane + 64 * i], s);
    #pragma unroll
    for (int off = 32; off > 0; off >>= 1) s += __shfl_down(s, off);
    if (lane == 0) out[b * VDIM + o] = s + mb[o];
}

extern "C" void kernel_launch(void* const* d_in, const int* in_sizes, int n_in,
                              void* d_out, int out_size, void* d_ws, size_t ws_size,
                              hipStream_t stream) {
    const float* dec     = (const float*)d_in[0];
    const float* enc     = (const float*)d_in[1];
    const int*   enc_len = (const int*)d_in[2];
    const float* Wq      = (const float*)d_in[3];
    const float* bq      = (const float*)d_in[4];
    const float* Wk      = (const float*)d_in[5];
    const float* bk      = (const float*)d_in[6];
    const float* Wv      = (const float*)d_in[7];
    const float* bv      = (const float*)d_in[8];
    const float* convw   = (const float*)d_in[9];
    const float* projw   = (const float*)d_in[10];
    const float* gen_w   = (const float*)d_in[11];
    const float* gen_b   = (const float*)d_in[12];
    const float* merge_w = (const float*)d_in[13];
    const float* merge_b = (const float*)d_in[14];

    float* out   = (float*)d_out;               // attn [65536] ++ context [4096]
    float* ws    = (float*)d_ws;
    float* query = ws + WS_QUERY;
    float* Qtab  = ws + WS_QTAB;
    float* energy= ws + WS_ENERGY;
    float* ctx   = ws + WS_CTX;
    float* locI  = ws + WS_LOCI;
    float* Pws   = ws + WS_P;
    __bf16* enc_bf = (__bf16*)((char*)d_ws + (size_t)WS_F32_END * 4);
    __bf16* wk_bf  = enc_bf + (size_t)BS * TS * VDIM;
    __bf16* wv_bf  = wk_bf + (size_t)NHD * VDIM;

    // zero atomic accumulators (energy + ctx contiguous)
    hipMemsetAsync(energy, 0, (65536 + 16384) * sizeof(float), stream);

    k_cvt3<<<dim3((NE4 + 2 * NW4) / 256), dim3(256), 0, stream>>>(
        enc, Wk, Wv, enc_bf, wk_bf, wv_bf);
    k_query<<<dim3(BS * NHD / 4), dim3(256), 0, stream>>>(dec, Wq, bq, query);
    k_prefix<<<dim3(1), dim3(128), 0, stream>>>(convw, Pws);
    k_qtab<<<dim3(2 * KS + 2), dim3(512), 0, stream>>>(Pws, projw, Qtab);
    k_locI<<<dim3(BS * DIM / 256), dim3(256), 0, stream>>>(Qtab, enc_len, locI);
    k_energy<<<dim3(TS / 128, NHD / 128, BS), dim3(512), 0, stream>>>(
        enc_bf, wk_bf, bk, gen_w, enc_len, query, Qtab, locI, energy);
    k_softmax<<<dim3(BS * NH), dim3(512), 0, stream>>>(energy, enc_len, gen_b, out);
    k_ctx<<<dim3(TS / 128, NHD / 128, BS), dim3(512), 0, stream>>>(
        enc_bf, wv_bf, bv, out, enc_len, ctx);
    k_merge<<<dim3(BS * VDIM / 4), dim3(256), 0, stream>>>(ctx, merge_w, merge_b, out + 65536);
}